// Round 3
// baseline (1828.470 us; speedup 1.0000x reference)
//
#include <hip/hip_runtime.h>
#include <hip/hip_bf16.h>
#include <math.h>

#define S_LEN 512
#define B_SZ  256
#define I_SZ  227
#define H_SZ  100
#define T_SZ  19

__device__ __forceinline__ float tanh_fast(float x) {
    // tanh(x) = 1 - 2/(exp(2x)+1); exp overflow -> inf -> 1, underflow -> -1. OK.
    float e = __expf(2.0f * x);
    return 1.0f - 2.0f / (e + 1.0f);
}

// ---------------------------------------------------------------------------
// K1: input projection. out[s,b,j] = x[s,b,:]·w[j,:] + b[j] for 200 j
//     (100 fwd + 100 bwd). Block = 256 thr (4 waves), 64 rows.
//     x tile in LDS [64][228] (57 odd b128-groups -> conflict-free per-lane
//     reads). Each wave owns 50 j in 2 chunks of 25; chunk w rows staged in a
//     wave-private LDS buffer [25][228] and read as WAVE-UNIFORM float4
//     (broadcast, ~1 LDS phase) -> no per-FMA VMEM, no bank conflicts.
//     Dynamic LDS total = (64 + 4*25) * 228 * 4 = 149568 B (1 block/CU).
// ---------------------------------------------------------------------------
#define XTP 228
#define K1_LDS ((64 + 4 * 25) * XTP * 4)

__global__ __launch_bounds__(256, 1)
void k1_inproj(const float* __restrict__ x,
               const float* __restrict__ w_ih_f, const float* __restrict__ b_ih_f,
               const float* __restrict__ w_ih_b, const float* __restrict__ b_ih_b,
               float* __restrict__ xf, float* __restrict__ xb) {
    extern __shared__ float smem[];
    float* lx = smem;                        // [64][228]
    const int tid  = threadIdx.x;
    const int lane = tid & 63;
    const int wv   = __builtin_amdgcn_readfirstlane(tid >> 6);   // 0..3
    float* lwv = smem + 64 * XTP + wv * 25 * XTP;                // [25][228]
    const long m0  = (long)blockIdx.x * 64;

    // ---- stage x tile: flat coalesced f4 loads, scalar LDS writes w/ pad fix
    {
        const float* xsrc = x + m0 * I_SZ;   // 16B-aligned (m0*227*4 % 16 == 0)
        for (int i = tid; i < 3632; i += 256) {
            float4 v = ((const float4*)xsrc)[i];
            int f = i * 4;
            #pragma unroll
            for (int e = 0; e < 4; ++e) {
                int fe = f + e;
                int r  = fe / I_SZ;
                int c  = fe - r * I_SZ;
                float val = (e == 0) ? v.x : (e == 1) ? v.y : (e == 2) ? v.z : v.w;
                lx[r * XTP + c] = val;
            }
        }
    }
    __syncthreads();

    const int jb = wv * 50;                  // uniform
    const float* xrow = lx + lane * XTP;

    float acc[50];
    #pragma unroll
    for (int u = 0; u < 50; ++u) {
        int j = jb + u;                      // uniform
        acc[u] = (j < 100) ? b_ih_f[j] : b_ih_b[j - 100];
    }

    #pragma unroll
    for (int c = 0; c < 2; ++c) {
        const int j0 = jb + c * 25;          // uniform; never crosses j=100
        const float* ws = (j0 < 100) ? (w_ih_f + (long)j0 * I_SZ)
                                     : (w_ih_b + (long)(j0 - 100) * I_SZ);
        // stage 25 w rows (wave-private buffer): coalesced scalar loads
        #pragma unroll
        for (int u = 0; u < 25; ++u)
            for (int i = lane; i < I_SZ; i += 64)
                lwv[u * XTP + i] = ws[u * I_SZ + i];
        __syncthreads();                     // uniform control flow; cheap

        for (int k = 0; k < 224; k += 4) {
            float4 xv = *(const float4*)(xrow + k);
            #pragma unroll
            for (int u = 0; u < 25; ++u) {
                float4 wvv = *(const float4*)(lwv + u * XTP + k);  // uniform bcast
                acc[c * 25 + u] = fmaf(xv.x, wvv.x, acc[c * 25 + u]);
                acc[c * 25 + u] = fmaf(xv.y, wvv.y, acc[c * 25 + u]);
                acc[c * 25 + u] = fmaf(xv.z, wvv.z, acc[c * 25 + u]);
                acc[c * 25 + u] = fmaf(xv.w, wvv.w, acc[c * 25 + u]);
            }
        }
        #pragma unroll
        for (int k = 224; k < 227; ++k) {
            float xv = xrow[k];
            #pragma unroll
            for (int u = 0; u < 25; ++u)
                acc[c * 25 + u] = fmaf(xv, lwv[u * XTP + k], acc[c * 25 + u]);
        }
        __syncthreads();                     // before next chunk overwrites lwv
    }

    // ---- output staging: reuse lx as lout (12800 floats), coalesced f4 out
    #pragma unroll
    for (int u = 0; u < 50; ++u) {
        int j = jb + u;
        int base = (j < 100) ? (lane * 100 + j) : (6400 + lane * 100 + (j - 100));
        lx[base] = acc[u];
    }
    __syncthreads();

    float* dstf = xf + m0 * 100;             // block regions contiguous
    float* dstb = xb + m0 * 100;
    for (int i = tid; i < 1600; i += 256) {
        ((float4*)dstf)[i] = ((const float4*)lx)[i];
        ((float4*)dstb)[i] = ((const float4*)(lx + 6400))[i];
    }
}

// ---------------------------------------------------------------------------
// K2: Elman RNN scan, both dirs. One block per (b,dir); 128 thr (j = tid).
//     Replicated-h: every lane FMAs the shared h vector (wave-uniform float4
//     LDS broadcasts) against its private W_hh row held in VGPRs (104 regs,
//     zero-padded). h written in-place over xproj. One barrier per step.
// ---------------------------------------------------------------------------
#define HPAD 104
__global__ __launch_bounds__(128, 1)
void k2_rnn(const float* __restrict__ w_hh_f, const float* __restrict__ b_hh_f,
            const float* __restrict__ w_hh_b, const float* __restrict__ b_hh_b,
            float* __restrict__ xf, float* __restrict__ xb) {
    __shared__ float hbuf[2][HPAD];
    const int tid = threadIdx.x;             // j = tid, valid < 100
    const int j   = tid;
    const int b   = blockIdx.x & 255;
    const int dir = blockIdx.x >> 8;

    const float* whh = dir ? w_hh_b : w_hh_f;
    const float* bhh = dir ? b_hh_b : b_hh_f;
    float* xp        = dir ? xb : xf;

    float wreg[HPAD];
    #pragma unroll
    for (int k = 0; k < HPAD; ++k) wreg[k] = 0.f;
    float bias = 0.f;
    if (j < 100) {
        bias = bhh[j];
        #pragma unroll
        for (int k = 0; k < 100; ++k) wreg[k] = whh[j * 100 + k];
    }
    if (tid < HPAD) { hbuf[0][tid] = 0.f; hbuf[1][tid] = 0.f; }
    __syncthreads();

    const int jj = (j < 100) ? j : 0;        // clamped addr for idle lanes
    float cur = xp[((long)(dir ? S_LEN - 1 : 0) * B_SZ + b) * 100 + jj];

    int p = 0;
    for (int t = 0; t < S_LEN; ++t) {
        const int s  = dir ? (S_LEN - 1 - t) : t;
        const int t2 = (t + 1 < S_LEN) ? (t + 1) : t;
        const int sn = dir ? (S_LEN - 1 - t2) : t2;
        float nxt = xp[((long)sn * B_SZ + b) * 100 + jj];    // prefetch

        float a0 = bias, a1 = 0.f, a2 = 0.f, a3 = 0.f;
        #pragma unroll
        for (int kk = 0; kk < 26; ++kk) {
            float4 hv = *(const float4*)&hbuf[p][kk * 4];    // uniform -> broadcast
            a0 = fmaf(wreg[4 * kk],     hv.x, a0);
            a1 = fmaf(wreg[4 * kk + 1], hv.y, a1);
            a2 = fmaf(wreg[4 * kk + 2], hv.z, a2);
            a3 = fmaf(wreg[4 * kk + 3], hv.w, a3);
        }
        float hval = tanh_fast(cur + ((a0 + a1) + (a2 + a3)));
        if (j < 100) {
            xp[((long)s * B_SZ + b) * 100 + j] = hval;       // in-place h
            hbuf[p ^ 1][j] = hval;
        }
        __syncthreads();
        p ^= 1;
        cur = nxt;
    }
}

// ---------------------------------------------------------------------------
// K4: emissions[s,b,t] = [hf|hb]·W_tag[t,:] + b_tag[t].
//     W_tag (15.2 KB) staged in LDS, read wave-uniform (broadcast). Each
//     thread reads its own h row as aligned float4, computes 5 tags, stages
//     block's 64x19 tile in LDS, coalesced f4 stores.
// ---------------------------------------------------------------------------
__global__ __launch_bounds__(256, 4)
void k4_emis(const float* __restrict__ hf, const float* __restrict__ hb,
             const float* __restrict__ W_tag, const float* __restrict__ b_tag,
             float* __restrict__ em) {
    __shared__ float lw[T_SZ * 200];        // 15.2 KB
    __shared__ float lout[64 * T_SZ];       // 4.9 KB
    const int tid = threadIdx.x;
    const long m0 = (long)blockIdx.x * 64;

    for (int i = tid; i < 950; i += 256)    // 3800 floats = 950 float4
        ((float4*)lw)[i] = ((const float4*)W_tag)[i];
    __syncthreads();

    const int r  = tid & 63;
    const int tg = __builtin_amdgcn_readfirstlane(tid >> 6);  // uniform 0..3
    const float* hfr = hf + (m0 + r) * 100;  // 400B-aligned -> float4 ok
    const float* hbr = hb + (m0 + r) * 100;

    float acc[5];
    #pragma unroll
    for (int u = 0; u < 5; ++u) {
        int t = tg + 4 * u;
        acc[u] = (t < T_SZ) ? b_tag[t] : 0.f;
    }
    for (int k = 0; k < 100; k += 4) {
        float4 hv = *(const float4*)(hfr + k);
        float4 gv = *(const float4*)(hbr + k);
        #pragma unroll
        for (int u = 0; u < 5; ++u) {
            int t = tg + 4 * u;
            if (t < T_SZ) {
                float4 wv = *(const float4*)&lw[t * 200 + k];        // broadcast
                float4 vv = *(const float4*)&lw[t * 200 + 100 + k];  // broadcast
                acc[u] = fmaf(hv.x, wv.x, acc[u]); acc[u] = fmaf(hv.y, wv.y, acc[u]);
                acc[u] = fmaf(hv.z, wv.z, acc[u]); acc[u] = fmaf(hv.w, wv.w, acc[u]);
                acc[u] = fmaf(gv.x, vv.x, acc[u]); acc[u] = fmaf(gv.y, vv.y, acc[u]);
                acc[u] = fmaf(gv.z, vv.z, acc[u]); acc[u] = fmaf(gv.w, vv.w, acc[u]);
            }
        }
    }
    #pragma unroll
    for (int u = 0; u < 5; ++u) {
        int t = tg + 4 * u;
        if (t < T_SZ) lout[r * T_SZ + t] = acc[u];
    }
    __syncthreads();

    float* dst = em + m0 * T_SZ;             // contiguous 1216 floats = 304 f4
    for (int i = tid; i < 304; i += 256)
        ((float4*)dst)[i] = ((const float4*)lout)[i];
}

// ---------------------------------------------------------------------------
// K5: CRF numerator per batch. One 64-thr block per b.
// ---------------------------------------------------------------------------
__global__ __launch_bounds__(64)
void k5_numer(const int* __restrict__ tags, const float* __restrict__ em,
              const float* __restrict__ trans, const float* __restrict__ start_t,
              const float* __restrict__ end_t, float* __restrict__ num) {
    const int b   = blockIdx.x;
    const int tid = threadIdx.x;
    float acc = 0.f;
    #pragma unroll
    for (int i = 0; i < 8; ++i) {
        int s  = tid + i * 64;
        int ts = tags[(long)s * B_SZ + b];
        acc += em[((long)s * B_SZ + b) * T_SZ + ts];
        if (s < S_LEN - 1) {
            int tn = tags[(long)(s + 1) * B_SZ + b];
            acc += trans[ts * T_SZ + tn];
        }
    }
    if (tid == 0)  acc += start_t[tags[b]];
    if (tid == 63) acc += end_t[tags[(long)(S_LEN - 1) * B_SZ + b]];
    #pragma unroll
    for (int off = 32; off; off >>= 1) acc += __shfl_down(acc, off, 64);
    if (tid == 0) num[b] = acc;
}

// ---------------------------------------------------------------------------
// K6: CRF forward DP + final reduce. 1 wave/block, 3 batches/wave (lanes
//     (bl,j), 57 active). texp[i]=exp(trans[i][j]) in VGPRs. Double-buffered
//     score rows -> ONE barrier per step; per-lane local exps; max tree.
// ---------------------------------------------------------------------------
__global__ __launch_bounds__(64)
void k6_crf(const float* __restrict__ em, const float* __restrict__ trans,
            const float* __restrict__ start_t, const float* __restrict__ end_t,
            const float* __restrict__ num, float* __restrict__ out) {
    __shared__ float sbuf[2][3][20];        // rows 80B -> f4-aligned
    const int tid = threadIdx.x;
    const int bl  = tid / T_SZ;             // 0..2 for tid<57
    const int j   = tid - bl * T_SZ;
    const int b   = blockIdx.x * 3 + bl;
    const bool act = (tid < 57) && (b < B_SZ);

    float texp[T_SZ];
    float score = 0.f, em_cur = 0.f;
    if (act) {
        #pragma unroll
        for (int i = 0; i < T_SZ; ++i) texp[i] = __expf(trans[i * T_SZ + j]);
        score  = start_t[j] + em[(long)b * T_SZ + j];            // s=0
        em_cur = em[((long)1 * B_SZ + b) * T_SZ + j];            // prefetch s=1
    }

    int buf = 0;
    for (int s = 1; s < S_LEN; ++s) {
        float em_nxt = 0.f;
        if (act) {
            int sn = (s + 1 < S_LEN) ? (s + 1) : s;
            em_nxt = em[((long)sn * B_SZ + b) * T_SZ + j];       // prefetch
            sbuf[buf][bl][j] = score;
        }
        __syncthreads();
        if (act) {
            float4 v0 = *(const float4*)&sbuf[buf][bl][0];
            float4 v1 = *(const float4*)&sbuf[buf][bl][4];
            float4 v2 = *(const float4*)&sbuf[buf][bl][8];
            float4 v3 = *(const float4*)&sbuf[buf][bl][12];
            float4 v4 = *(const float4*)&sbuf[buf][bl][16];      // .w unused
            float sc[T_SZ] = {v0.x,v0.y,v0.z,v0.w, v1.x,v1.y,v1.z,v1.w,
                              v2.x,v2.y,v2.z,v2.w, v3.x,v3.y,v3.z,v3.w,
                              v4.x,v4.y,v4.z};
            float m = sc[0];
            #pragma unroll
            for (int i = 0; i < 9; ++i) m = fmaxf(fmaxf(m, sc[2*i+1]), sc[2*i+2]);
            float sum = 0.f;
            #pragma unroll
            for (int i = 0; i < T_SZ; ++i) sum = fmaf(__expf(sc[i] - m), texp[i], sum);
            score = m + __logf(sum) + em_cur;
        }
        em_cur = em_nxt;
        buf ^= 1;
    }

    if (act) sbuf[0][bl][j] = score + end_t[j];
    __syncthreads();
    if (act && j == 0) {
        float m = -1e30f;
        #pragma unroll
        for (int i = 0; i < T_SZ; ++i) m = fmaxf(m, sbuf[0][bl][i]);
        float sum = 0.f;
        #pragma unroll
        for (int i = 0; i < T_SZ; ++i) sum += __expf(sbuf[0][bl][i] - m);
        atomicAdd(out, num[b] - (m + __logf(sum)));
    }
}

// ---------------------------------------------------------------------------
extern "C" void kernel_launch(void* const* d_in, const int* in_sizes, int n_in,
                              void* d_out, int out_size, void* d_ws, size_t ws_size,
                              hipStream_t stream) {
    const float* x       = (const float*)d_in[0];
    const int*   tags    = (const int*)  d_in[1];
    const float* w_ih_f  = (const float*)d_in[2];
    const float* w_hh_f  = (const float*)d_in[3];
    const float* b_ih_f  = (const float*)d_in[4];
    const float* b_hh_f  = (const float*)d_in[5];
    const float* w_ih_b  = (const float*)d_in[6];
    const float* w_hh_b  = (const float*)d_in[7];
    const float* b_ih_b  = (const float*)d_in[8];
    const float* b_hh_b  = (const float*)d_in[9];
    const float* W_tag   = (const float*)d_in[10];
    const float* b_tag   = (const float*)d_in[11];
    const float* start_t = (const float*)d_in[12];
    const float* end_t   = (const float*)d_in[13];
    const float* trans   = (const float*)d_in[14];

    float* ws = (float*)d_ws;
    float* xf  = ws;                         // 13,107,200 fl (becomes hf in-place)
    float* xb  = xf + 13107200;              // 13,107,200 fl (becomes hb in-place)
    float* em  = xb + 13107200;              //  2,490,368 fl
    float* num = em + 2490368;               //        256 fl   (~114.8 MB total)

    // allow >64KB dynamic LDS for k1 (gfx950 supports up to 160KB/workgroup)
    hipFuncSetAttribute((const void*)k1_inproj,
                        hipFuncAttributeMaxDynamicSharedMemorySize, K1_LDS);

    k1_inproj<<<2048, 256, K1_LDS, stream>>>(x, w_ih_f, b_ih_f, w_ih_b, b_ih_b, xf, xb);
    k2_rnn   <<<512, 128, 0, stream>>>(w_hh_f, b_hh_f, w_hh_b, b_hh_b, xf, xb);
    k4_emis  <<<2048, 256, 0, stream>>>(xf, xb, W_tag, b_tag, em);
    k5_numer <<<256, 64, 0, stream>>>(tags, em, trans, start_t, end_t, num);
    hipMemsetAsync(d_out, 0, sizeof(float), stream);
    k6_crf   <<<86, 64, 0, stream>>>(em, trans, start_t, end_t, num, (float*)d_out);
}

// Round 10
// 1387.497 us; speedup vs baseline: 1.3178x; 1.3178x over previous
//
#include <hip/hip_runtime.h>
#include <hip/hip_bf16.h>
#include <math.h>

#define S_LEN 512
#define B_SZ  256
#define I_SZ  227
#define H_SZ  100
#define T_SZ  19

__device__ __forceinline__ float tanh_fast(float x) {
    // tanh(x) = 1 - 2/(exp(2x)+1); exp overflow -> inf -> 1, underflow -> -1. OK.
    float e = __expf(2.0f * x);
    return 1.0f - 2.0f / (e + 1.0f);
}

// ---------------------------------------------------------------------------
// K0: pack W rows into wpad[200][232]: 928B rows (16B aligned), cols 227..231
//     zero. Rows 0..99 = w_ih_f, 100..199 = w_ih_b. Enables float4 w-loads.
// ---------------------------------------------------------------------------
#define WP 232
__global__ __launch_bounds__(256)
void k0_packw(const float* __restrict__ w_ih_f, const float* __restrict__ w_ih_b,
              float* __restrict__ wpad) {
    const int j = blockIdx.x;               // 0..199
    const int c = threadIdx.x;              // 0..255
    if (c < WP) {
        float v = 0.f;
        if (c < I_SZ) v = (j < 100) ? w_ih_f[j * I_SZ + c] : w_ih_b[(j - 100) * I_SZ + c];
        wpad[j * WP + c] = v;
    }
}

// ---------------------------------------------------------------------------
// K1: input projection. out[s,b,j] = x[s,b,:]·w[j,:] + b[j], j<200.
//     Block 256 thr (4 waves), 64 x-rows in LDS [64][236] (row stride 944B:
//     59 banks/row, gcd(59,32)=1 -> conflict-free per-lane b128 reads; 16B
//     aligned). Wave q owns j in [50q,50q+50) in 5 groups of 10; w read as
//     WAVE-UNIFORM float4 from wpad (one SMEM/VMEM broadcast per 4 FMAs/j).
//     Inner step: 1 lane ds_read_b128 + 10 uniform f4 + 40 FMA -> VALU-bound.
//     acc in regs; output staged via LDS for coalesced f4 stores.
// ---------------------------------------------------------------------------
#define XTP 236
__global__ __launch_bounds__(256, 2)
void k1_inproj(const float* __restrict__ x, const float* __restrict__ wpad,
               const float* __restrict__ b_ih_f, const float* __restrict__ b_ih_b,
               float* __restrict__ xf, float* __restrict__ xb) {
    __shared__ float lx[64 * XTP];          // 60416 B -> 2 blocks/CU
    const int tid  = threadIdx.x;
    const int lane = tid & 63;
    const long m0  = (long)blockIdx.x * 64;

    // ---- stage x tile: flat coalesced f4 loads; r = fe/227 via magic mul
    {
        const float* xsrc = x + m0 * I_SZ;  // 16B aligned: 64*227*4 % 16 == 0
        for (int i = tid; i < 3632; i += 256) {
            float4 v = ((const float4*)xsrc)[i];
            int f = i * 4;
            #pragma unroll
            for (int e = 0; e < 4; ++e) {
                int fe = f + e;
                int r  = (int)(((unsigned long long)fe * 36955u) >> 23);  // fe/227
                int c  = fe - r * I_SZ;
                float val = (e == 0) ? v.x : (e == 1) ? v.y : (e == 2) ? v.z : v.w;
                lx[r * XTP + c] = val;
            }
        }
        if (tid < 64) lx[tid * XTP + 227] = 0.f;   // col 227 zero (w pad covers rest)
    }
    __syncthreads();

    const int jb = __builtin_amdgcn_readfirstlane(tid >> 6) * 50;   // uniform
    const float* xrow = lx + lane * XTP;

    float acc[50];
    #pragma unroll
    for (int u = 0; u < 50; ++u) {
        int j = jb + u;                      // uniform
        acc[u] = (j < 100) ? b_ih_f[j] : b_ih_b[j - 100];
    }

    #pragma unroll
    for (int g = 0; g < 5; ++g) {
        const int j0 = jb + g * 10;          // uniform
        const float* wr[10];
        #pragma unroll
        for (int u = 0; u < 10; ++u) wr[u] = wpad + (long)(j0 + u) * WP;

        for (int k = 0; k < 228; k += 4) {   // 57 exact f4 steps (zero-padded)
            float4 xv = *(const float4*)(xrow + k);
            #pragma unroll
            for (int u = 0; u < 10; ++u) {
                float4 wv = *(const float4*)(wr[u] + k);   // uniform -> broadcast
                acc[g * 10 + u] = fmaf(xv.x, wv.x, acc[g * 10 + u]);
                acc[g * 10 + u] = fmaf(xv.y, wv.y, acc[g * 10 + u]);
                acc[g * 10 + u] = fmaf(xv.z, wv.z, acc[g * 10 + u]);
                acc[g * 10 + u] = fmaf(xv.w, wv.w, acc[g * 10 + u]);
            }
        }
    }

    // ---- output staging: reuse lx (12800 floats <= 64*236), coalesced f4 out
    __syncthreads();
    #pragma unroll
    for (int u = 0; u < 50; ++u) {
        int j = jb + u;
        int base = (j < 100) ? (lane * 100 + j) : (6400 + lane * 100 + (j - 100));
        lx[base] = acc[u];
    }
    __syncthreads();

    float* dstf = xf + m0 * 100;             // block regions contiguous
    float* dstb = xb + m0 * 100;
    for (int i = tid; i < 1600; i += 256) {
        ((float4*)dstf)[i] = ((const float4*)lx)[i];
        ((float4*)dstb)[i] = ((const float4*)(lx + 6400))[i];
    }
}

// ---------------------------------------------------------------------------
// K2: Elman RNN scan, both dirs. One block per (b,dir); 128 thr (j = tid).
//     Replicated-h: every lane FMAs the shared h vector (wave-uniform float4
//     LDS broadcasts) against its private W_hh row held in VGPRs (104 regs,
//     zero-padded). h written in-place over xproj. One barrier per step.
// ---------------------------------------------------------------------------
#define HPAD 104
__global__ __launch_bounds__(128, 1)
void k2_rnn(const float* __restrict__ w_hh_f, const float* __restrict__ b_hh_f,
            const float* __restrict__ w_hh_b, const float* __restrict__ b_hh_b,
            float* __restrict__ xf, float* __restrict__ xb) {
    __shared__ float hbuf[2][HPAD];
    const int tid = threadIdx.x;             // j = tid, valid < 100
    const int j   = tid;
    const int b   = blockIdx.x & 255;
    const int dir = blockIdx.x >> 8;

    const float* whh = dir ? w_hh_b : w_hh_f;
    const float* bhh = dir ? b_hh_b : b_hh_f;
    float* xp        = dir ? xb : xf;

    float wreg[HPAD];
    #pragma unroll
    for (int k = 0; k < HPAD; ++k) wreg[k] = 0.f;
    float bias = 0.f;
    if (j < 100) {
        bias = bhh[j];
        #pragma unroll
        for (int k = 0; k < 100; ++k) wreg[k] = whh[j * 100 + k];
    }
    if (tid < HPAD) { hbuf[0][tid] = 0.f; hbuf[1][tid] = 0.f; }
    __syncthreads();

    const int jj = (j < 100) ? j : 0;        // clamped addr for idle lanes
    float cur = xp[((long)(dir ? S_LEN - 1 : 0) * B_SZ + b) * 100 + jj];

    int p = 0;
    for (int t = 0; t < S_LEN; ++t) {
        const int s  = dir ? (S_LEN - 1 - t) : t;
        const int t2 = (t + 1 < S_LEN) ? (t + 1) : t;
        const int sn = dir ? (S_LEN - 1 - t2) : t2;
        float nxt = xp[((long)sn * B_SZ + b) * 100 + jj];    // prefetch

        float a0 = bias, a1 = 0.f, a2 = 0.f, a3 = 0.f;
        #pragma unroll
        for (int kk = 0; kk < 26; ++kk) {
            float4 hv = *(const float4*)&hbuf[p][kk * 4];    // uniform -> broadcast
            a0 = fmaf(wreg[4 * kk],     hv.x, a0);
            a1 = fmaf(wreg[4 * kk + 1], hv.y, a1);
            a2 = fmaf(wreg[4 * kk + 2], hv.z, a2);
            a3 = fmaf(wreg[4 * kk + 3], hv.w, a3);
        }
        float hval = tanh_fast(cur + ((a0 + a1) + (a2 + a3)));
        if (j < 100) {
            xp[((long)s * B_SZ + b) * 100 + j] = hval;       // in-place h
            hbuf[p ^ 1][j] = hval;
        }
        __syncthreads();
        p ^= 1;
        cur = nxt;
    }
}

// ---------------------------------------------------------------------------
// K4: emissions[s,b,t] = [hf|hb]·W_tag[t,:] + b_tag[t].
//     W_tag (15.2 KB) staged in LDS, read wave-uniform (broadcast). Each
//     thread reads its own h row as aligned float4, computes 5 tags, stages
//     block's 64x19 tile in LDS, coalesced f4 stores.
// ---------------------------------------------------------------------------
__global__ __launch_bounds__(256, 4)
void k4_emis(const float* __restrict__ hf, const float* __restrict__ hb,
             const float* __restrict__ W_tag, const float* __restrict__ b_tag,
             float* __restrict__ em) {
    __shared__ float lw[T_SZ * 200];        // 15.2 KB
    __shared__ float lout[64 * T_SZ];       // 4.9 KB
    const int tid = threadIdx.x;
    const long m0 = (long)blockIdx.x * 64;

    for (int i = tid; i < 950; i += 256)    // 3800 floats = 950 float4
        ((float4*)lw)[i] = ((const float4*)W_tag)[i];
    __syncthreads();

    const int r  = tid & 63;
    const int tg = __builtin_amdgcn_readfirstlane(tid >> 6);  // uniform 0..3
    const float* hfr = hf + (m0 + r) * 100;  // 400B-aligned -> float4 ok
    const float* hbr = hb + (m0 + r) * 100;

    float acc[5];
    #pragma unroll
    for (int u = 0; u < 5; ++u) {
        int t = tg + 4 * u;
        acc[u] = (t < T_SZ) ? b_tag[t] : 0.f;
    }
    for (int k = 0; k < 100; k += 4) {
        float4 hv = *(const float4*)(hfr + k);
        float4 gv = *(const float4*)(hbr + k);
        #pragma unroll
        for (int u = 0; u < 5; ++u) {
            int t = tg + 4 * u;
            if (t < T_SZ) {
                float4 wv = *(const float4*)&lw[t * 200 + k];        // broadcast
                float4 vv = *(const float4*)&lw[t * 200 + 100 + k];  // broadcast
                acc[u] = fmaf(hv.x, wv.x, acc[u]); acc[u] = fmaf(hv.y, wv.y, acc[u]);
                acc[u] = fmaf(hv.z, wv.z, acc[u]); acc[u] = fmaf(hv.w, wv.w, acc[u]);
                acc[u] = fmaf(gv.x, vv.x, acc[u]); acc[u] = fmaf(gv.y, vv.y, acc[u]);
                acc[u] = fmaf(gv.z, vv.z, acc[u]); acc[u] = fmaf(gv.w, vv.w, acc[u]);
            }
        }
    }
    #pragma unroll
    for (int u = 0; u < 5; ++u) {
        int t = tg + 4 * u;
        if (t < T_SZ) lout[r * T_SZ + t] = acc[u];
    }
    __syncthreads();

    float* dst = em + m0 * T_SZ;             // contiguous 1216 floats = 304 f4
    for (int i = tid; i < 304; i += 256)
        ((float4*)dst)[i] = ((const float4*)lout)[i];
}

// ---------------------------------------------------------------------------
// K5: CRF numerator per batch. One 64-thr block per b.
// ---------------------------------------------------------------------------
__global__ __launch_bounds__(64)
void k5_numer(const int* __restrict__ tags, const float* __restrict__ em,
              const float* __restrict__ trans, const float* __restrict__ start_t,
              const float* __restrict__ end_t, float* __restrict__ num) {
    const int b   = blockIdx.x;
    const int tid = threadIdx.x;
    float acc = 0.f;
    #pragma unroll
    for (int i = 0; i < 8; ++i) {
        int s  = tid + i * 64;
        int ts = tags[(long)s * B_SZ + b];
        acc += em[((long)s * B_SZ + b) * T_SZ + ts];
        if (s < S_LEN - 1) {
            int tn = tags[(long)(s + 1) * B_SZ + b];
            acc += trans[ts * T_SZ + tn];
        }
    }
    if (tid == 0)  acc += start_t[tags[b]];
    if (tid == 63) acc += end_t[tags[(long)(S_LEN - 1) * B_SZ + b]];
    #pragma unroll
    for (int off = 32; off; off >>= 1) acc += __shfl_down(acc, off, 64);
    if (tid == 0) num[b] = acc;
}

// ---------------------------------------------------------------------------
// K6: CRF forward DP + final reduce. 1 wave/block, 3 batches/wave (lanes
//     (bl,j), 57 active). texp[i]=exp(trans[i][j]) in VGPRs. Double-buffered
//     score rows -> ONE barrier per step; per-lane local exps; max tree.
// ---------------------------------------------------------------------------
__global__ __launch_bounds__(64)
void k6_crf(const float* __restrict__ em, const float* __restrict__ trans,
            const float* __restrict__ start_t, const float* __restrict__ end_t,
            const float* __restrict__ num, float* __restrict__ out) {
    __shared__ float sbuf[2][3][20];        // rows 80B -> f4-aligned
    const int tid = threadIdx.x;
    const int bl  = tid / T_SZ;             // 0..2 for tid<57
    const int j   = tid - bl * T_SZ;
    const int b   = blockIdx.x * 3 + bl;
    const bool act = (tid < 57) && (b < B_SZ);

    float texp[T_SZ];
    float score = 0.f, em_cur = 0.f;
    if (act) {
        #pragma unroll
        for (int i = 0; i < T_SZ; ++i) texp[i] = __expf(trans[i * T_SZ + j]);
        score  = start_t[j] + em[(long)b * T_SZ + j];            // s=0
        em_cur = em[((long)1 * B_SZ + b) * T_SZ + j];            // prefetch s=1
    }

    int buf = 0;
    for (int s = 1; s < S_LEN; ++s) {
        float em_nxt = 0.f;
        if (act) {
            int sn = (s + 1 < S_LEN) ? (s + 1) : s;
            em_nxt = em[((long)sn * B_SZ + b) * T_SZ + j];       // prefetch
            sbuf[buf][bl][j] = score;
        }
        __syncthreads();
        if (act) {
            float4 v0 = *(const float4*)&sbuf[buf][bl][0];
            float4 v1 = *(const float4*)&sbuf[buf][bl][4];
            float4 v2 = *(const float4*)&sbuf[buf][bl][8];
            float4 v3 = *(const float4*)&sbuf[buf][bl][12];
            float4 v4 = *(const float4*)&sbuf[buf][bl][16];      // .w unused
            float sc[T_SZ] = {v0.x,v0.y,v0.z,v0.w, v1.x,v1.y,v1.z,v1.w,
                              v2.x,v2.y,v2.z,v2.w, v3.x,v3.y,v3.z,v3.w,
                              v4.x,v4.y,v4.z};
            float m = sc[0];
            #pragma unroll
            for (int i = 0; i < 9; ++i) m = fmaxf(fmaxf(m, sc[2*i+1]), sc[2*i+2]);
            float sum = 0.f;
            #pragma unroll
            for (int i = 0; i < T_SZ; ++i) sum = fmaf(__expf(sc[i] - m), texp[i], sum);
            score = m + __logf(sum) + em_cur;
        }
        em_cur = em_nxt;
        buf ^= 1;
    }

    if (act) sbuf[0][bl][j] = score + end_t[j];
    __syncthreads();
    if (act && j == 0) {
        float m = -1e30f;
        #pragma unroll
        for (int i = 0; i < T_SZ; ++i) m = fmaxf(m, sbuf[0][bl][i]);
        float sum = 0.f;
        #pragma unroll
        for (int i = 0; i < T_SZ; ++i) sum += __expf(sbuf[0][bl][i] - m);
        atomicAdd(out, num[b] - (m + __logf(sum)));
    }
}

// ---------------------------------------------------------------------------
extern "C" void kernel_launch(void* const* d_in, const int* in_sizes, int n_in,
                              void* d_out, int out_size, void* d_ws, size_t ws_size,
                              hipStream_t stream) {
    const float* x       = (const float*)d_in[0];
    const int*   tags    = (const int*)  d_in[1];
    const float* w_ih_f  = (const float*)d_in[2];
    const float* w_hh_f  = (const float*)d_in[3];
    const float* b_ih_f  = (const float*)d_in[4];
    const float* b_hh_f  = (const float*)d_in[5];
    const float* w_ih_b  = (const float*)d_in[6];
    const float* w_hh_b  = (const float*)d_in[7];
    const float* b_ih_b  = (const float*)d_in[8];
    const float* b_hh_b  = (const float*)d_in[9];
    const float* W_tag   = (const float*)d_in[10];
    const float* b_tag   = (const float*)d_in[11];
    const float* start_t = (const float*)d_in[12];
    const float* end_t   = (const float*)d_in[13];
    const float* trans   = (const float*)d_in[14];

    float* ws = (float*)d_ws;
    float* xf   = ws;                        // 13,107,200 fl (becomes hf in-place)
    float* xb   = xf + 13107200;             // 13,107,200 fl (becomes hb in-place)
    float* em   = xb + 13107200;             //  2,490,368 fl
    float* num  = em + 2490368;              //        256 fl
    float* wpad = num + 256;                 //     46,400 fl   (~115 MB total)

    k0_packw <<<200, 256, 0, stream>>>(w_ih_f, w_ih_b, wpad);
    k1_inproj<<<2048, 256, 0, stream>>>(x, wpad, b_ih_f, b_ih_b, xf, xb);
    k2_rnn   <<<512, 128, 0, stream>>>(w_hh_f, b_hh_f, w_hh_b, b_hh_b, xf, xb);
    k4_emis  <<<2048, 256, 0, stream>>>(xf, xb, W_tag, b_tag, em);
    k5_numer <<<256, 64, 0, stream>>>(tags, em, trans, start_t, end_t, num);
    hipMemsetAsync(d_out, 0, sizeof(float), stream);
    k6_crf   <<<86, 64, 0, stream>>>(em, trans, start_t, end_t, num, (float*)d_out);
}

// Round 11
// 1384.902 us; speedup vs baseline: 1.3203x; 1.0019x over previous
//
#include <hip/hip_runtime.h>
#include <hip/hip_bf16.h>
#include <math.h>

#define S_LEN 512
#define B_SZ  256
#define I_SZ  227
#define H_SZ  100
#define T_SZ  19

__device__ __forceinline__ float tanh_fast(float x) {
    // tanh(x) = 1 - 2/(exp(2x)+1); exp overflow -> inf -> 1, underflow -> -1. OK.
    float e = __expf(2.0f * x);
    return 1.0f - 2.0f / (e + 1.0f);
}

// ---------------------------------------------------------------------------
// K0: pack W rows into wpad[200][232]: 928B rows (16B aligned), cols 227..231
//     zero. Rows 0..99 = w_ih_f, 100..199 = w_ih_b. Enables float4 w-loads.
// ---------------------------------------------------------------------------
#define WP 232
__global__ __launch_bounds__(256)
void k0_packw(const float* __restrict__ w_ih_f, const float* __restrict__ w_ih_b,
              float* __restrict__ wpad) {
    const int j = blockIdx.x;               // 0..199
    const int c = threadIdx.x;              // 0..255
    if (c < WP) {
        float v = 0.f;
        if (c < I_SZ) v = (j < 100) ? w_ih_f[j * I_SZ + c] : w_ih_b[(j - 100) * I_SZ + c];
        wpad[j * WP + c] = v;
    }
}

// ---------------------------------------------------------------------------
// K1: input projection. out[s,b,j] = x[s,b,:]·w[j,:] + b[j], j<200.
//     Round-10 PMC: VALUBusy 15%, conflicts negligible -> un-hidden VMEM
//     latency (10 w-loads then dependent FMAs, no unroll, 2 waves/SIMD).
//     FIX: register double-buffer — prefetch next k-step's 10 w-float4 + x
//     while FMA-ing current (rotate cw<-nw), peel final step. ~170 VGPR.
// ---------------------------------------------------------------------------
#define XTP 236
__global__ __launch_bounds__(256, 2)
void k1_inproj(const float* __restrict__ x, const float* __restrict__ wpad,
               const float* __restrict__ b_ih_f, const float* __restrict__ b_ih_b,
               float* __restrict__ xf, float* __restrict__ xb) {
    __shared__ float lx[64 * XTP];          // 60416 B -> 2 blocks/CU
    const int tid  = threadIdx.x;
    const int lane = tid & 63;
    const long m0  = (long)blockIdx.x * 64;

    // ---- stage x tile: flat coalesced f4 loads; r = fe/227 via magic mul
    {
        const float* xsrc = x + m0 * I_SZ;  // 16B aligned: 64*227*4 % 16 == 0
        for (int i = tid; i < 3632; i += 256) {
            float4 v = ((const float4*)xsrc)[i];
            int f = i * 4;
            #pragma unroll
            for (int e = 0; e < 4; ++e) {
                int fe = f + e;
                int r  = (int)(((unsigned long long)fe * 36955u) >> 23);  // fe/227
                int c  = fe - r * I_SZ;
                float val = (e == 0) ? v.x : (e == 1) ? v.y : (e == 2) ? v.z : v.w;
                lx[r * XTP + c] = val;
            }
        }
        if (tid < 64) lx[tid * XTP + 227] = 0.f;   // col 227 zero (w pad covers rest)
    }
    __syncthreads();

    const int jb = __builtin_amdgcn_readfirstlane(tid >> 6) * 50;   // uniform
    const float* xrow = lx + lane * XTP;

    float acc[50];
    #pragma unroll
    for (int u = 0; u < 50; ++u) {
        int j = jb + u;                      // uniform
        acc[u] = (j < 100) ? b_ih_f[j] : b_ih_b[j - 100];
    }

    for (int g = 0; g < 5; ++g) {
        const int j0 = jb + g * 10;          // uniform
        const float* wr[10];
        #pragma unroll
        for (int u = 0; u < 10; ++u) wr[u] = wpad + (long)(j0 + u) * WP;

        // ---- software-pipelined: prefetch k+4 while FMA-ing k
        float4 cw[10], nw[10];
        float4 cx = *(const float4*)(xrow);
        #pragma unroll
        for (int u = 0; u < 10; ++u) cw[u] = *(const float4*)(wr[u]);

        for (int k = 0; k < 224; k += 4) {   // 56 steps w/ prefetch
            float4 nx = *(const float4*)(xrow + k + 4);
            #pragma unroll
            for (int u = 0; u < 10; ++u) nw[u] = *(const float4*)(wr[u] + k + 4);
            #pragma unroll
            for (int u = 0; u < 10; ++u) {
                int a = g * 10 + u;
                acc[a] = fmaf(cx.x, cw[u].x, acc[a]);
                acc[a] = fmaf(cx.y, cw[u].y, acc[a]);
                acc[a] = fmaf(cx.z, cw[u].z, acc[a]);
                acc[a] = fmaf(cx.w, cw[u].w, acc[a]);
            }
            cx = nx;
            #pragma unroll
            for (int u = 0; u < 10; ++u) cw[u] = nw[u];
        }
        // ---- peeled final step k = 224 (cols 224..227, zero-padded)
        #pragma unroll
        for (int u = 0; u < 10; ++u) {
            int a = g * 10 + u;
            acc[a] = fmaf(cx.x, cw[u].x, acc[a]);
            acc[a] = fmaf(cx.y, cw[u].y, acc[a]);
            acc[a] = fmaf(cx.z, cw[u].z, acc[a]);
            acc[a] = fmaf(cx.w, cw[u].w, acc[a]);
        }
    }

    // ---- output staging: reuse lx (12800 floats <= 64*236), coalesced f4 out
    __syncthreads();
    #pragma unroll
    for (int u = 0; u < 50; ++u) {
        int j = jb + u;
        int base = (j < 100) ? (lane * 100 + j) : (6400 + lane * 100 + (j - 100));
        lx[base] = acc[u];
    }
    __syncthreads();

    float* dstf = xf + m0 * 100;             // block regions contiguous
    float* dstb = xb + m0 * 100;
    for (int i = tid; i < 1600; i += 256) {
        ((float4*)dstf)[i] = ((const float4*)lx)[i];
        ((float4*)dstb)[i] = ((const float4*)(lx + 6400))[i];
    }
}

// ---------------------------------------------------------------------------
// K2: Elman RNN scan, both dirs. One block per (b,dir); 128 thr (j = tid).
//     Replicated-h: every lane FMAs the shared h vector (wave-uniform float4
//     LDS broadcasts) against its private W_hh row held in VGPRs (104 regs,
//     zero-padded). h written in-place over xproj. One barrier per step.
// ---------------------------------------------------------------------------
#define HPAD 104
__global__ __launch_bounds__(128, 1)
void k2_rnn(const float* __restrict__ w_hh_f, const float* __restrict__ b_hh_f,
            const float* __restrict__ w_hh_b, const float* __restrict__ b_hh_b,
            float* __restrict__ xf, float* __restrict__ xb) {
    __shared__ float hbuf[2][HPAD];
    const int tid = threadIdx.x;             // j = tid, valid < 100
    const int j   = tid;
    const int b   = blockIdx.x & 255;
    const int dir = blockIdx.x >> 8;

    const float* whh = dir ? w_hh_b : w_hh_f;
    const float* bhh = dir ? b_hh_b : b_hh_f;
    float* xp        = dir ? xb : xf;

    float wreg[HPAD];
    #pragma unroll
    for (int k = 0; k < HPAD; ++k) wreg[k] = 0.f;
    float bias = 0.f;
    if (j < 100) {
        bias = bhh[j];
        #pragma unroll
        for (int k = 0; k < 100; ++k) wreg[k] = whh[j * 100 + k];
    }
    if (tid < HPAD) { hbuf[0][tid] = 0.f; hbuf[1][tid] = 0.f; }
    __syncthreads();

    const int jj = (j < 100) ? j : 0;        // clamped addr for idle lanes
    float cur = xp[((long)(dir ? S_LEN - 1 : 0) * B_SZ + b) * 100 + jj];

    int p = 0;
    for (int t = 0; t < S_LEN; ++t) {
        const int s  = dir ? (S_LEN - 1 - t) : t;
        const int t2 = (t + 1 < S_LEN) ? (t + 1) : t;
        const int sn = dir ? (S_LEN - 1 - t2) : t2;
        float nxt = xp[((long)sn * B_SZ + b) * 100 + jj];    // prefetch

        float a0 = bias, a1 = 0.f, a2 = 0.f, a3 = 0.f;
        #pragma unroll
        for (int kk = 0; kk < 26; ++kk) {
            float4 hv = *(const float4*)&hbuf[p][kk * 4];    // uniform -> broadcast
            a0 = fmaf(wreg[4 * kk],     hv.x, a0);
            a1 = fmaf(wreg[4 * kk + 1], hv.y, a1);
            a2 = fmaf(wreg[4 * kk + 2], hv.z, a2);
            a3 = fmaf(wreg[4 * kk + 3], hv.w, a3);
        }
        float hval = tanh_fast(cur + ((a0 + a1) + (a2 + a3)));
        if (j < 100) {
            xp[((long)s * B_SZ + b) * 100 + j] = hval;       // in-place h
            hbuf[p ^ 1][j] = hval;
        }
        __syncthreads();
        p ^= 1;
        cur = nxt;
    }
}

// ---------------------------------------------------------------------------
// K4: emissions[s,b,t] = [hf|hb]·W_tag[t,:] + b_tag[t].
//     W_tag (15.2 KB) staged in LDS, read wave-uniform (broadcast). Each
//     thread reads its own h row as aligned float4, computes 5 tags, stages
//     block's 64x19 tile in LDS, coalesced f4 stores.
// ---------------------------------------------------------------------------
__global__ __launch_bounds__(256, 4)
void k4_emis(const float* __restrict__ hf, const float* __restrict__ hb,
             const float* __restrict__ W_tag, const float* __restrict__ b_tag,
             float* __restrict__ em) {
    __shared__ float lw[T_SZ * 200];        // 15.2 KB
    __shared__ float lout[64 * T_SZ];       // 4.9 KB
    const int tid = threadIdx.x;
    const long m0 = (long)blockIdx.x * 64;

    for (int i = tid; i < 950; i += 256)    // 3800 floats = 950 float4
        ((float4*)lw)[i] = ((const float4*)W_tag)[i];
    __syncthreads();

    const int r  = tid & 63;
    const int tg = __builtin_amdgcn_readfirstlane(tid >> 6);  // uniform 0..3
    const float* hfr = hf + (m0 + r) * 100;  // 400B-aligned -> float4 ok
    const float* hbr = hb + (m0 + r) * 100;

    float acc[5];
    #pragma unroll
    for (int u = 0; u < 5; ++u) {
        int t = tg + 4 * u;
        acc[u] = (t < T_SZ) ? b_tag[t] : 0.f;
    }
    for (int k = 0; k < 100; k += 4) {
        float4 hv = *(const float4*)(hfr + k);
        float4 gv = *(const float4*)(hbr + k);
        #pragma unroll
        for (int u = 0; u < 5; ++u) {
            int t = tg + 4 * u;
            if (t < T_SZ) {
                float4 wv = *(const float4*)&lw[t * 200 + k];        // broadcast
                float4 vv = *(const float4*)&lw[t * 200 + 100 + k];  // broadcast
                acc[u] = fmaf(hv.x, wv.x, acc[u]); acc[u] = fmaf(hv.y, wv.y, acc[u]);
                acc[u] = fmaf(hv.z, wv.z, acc[u]); acc[u] = fmaf(hv.w, wv.w, acc[u]);
                acc[u] = fmaf(gv.x, vv.x, acc[u]); acc[u] = fmaf(gv.y, vv.y, acc[u]);
                acc[u] = fmaf(gv.z, vv.z, acc[u]); acc[u] = fmaf(gv.w, vv.w, acc[u]);
            }
        }
    }
    #pragma unroll
    for (int u = 0; u < 5; ++u) {
        int t = tg + 4 * u;
        if (t < T_SZ) lout[r * T_SZ + t] = acc[u];
    }
    __syncthreads();

    float* dst = em + m0 * T_SZ;             // contiguous 1216 floats = 304 f4
    for (int i = tid; i < 304; i += 256)
        ((float4*)dst)[i] = ((const float4*)lout)[i];
}

// ---------------------------------------------------------------------------
// K5: CRF numerator per batch. One 64-thr block per b.
// ---------------------------------------------------------------------------
__global__ __launch_bounds__(64)
void k5_numer(const int* __restrict__ tags, const float* __restrict__ em,
              const float* __restrict__ trans, const float* __restrict__ start_t,
              const float* __restrict__ end_t, float* __restrict__ num) {
    const int b   = blockIdx.x;
    const int tid = threadIdx.x;
    float acc = 0.f;
    #pragma unroll
    for (int i = 0; i < 8; ++i) {
        int s  = tid + i * 64;
        int ts = tags[(long)s * B_SZ + b];
        acc += em[((long)s * B_SZ + b) * T_SZ + ts];
        if (s < S_LEN - 1) {
            int tn = tags[(long)(s + 1) * B_SZ + b];
            acc += trans[ts * T_SZ + tn];
        }
    }
    if (tid == 0)  acc += start_t[tags[b]];
    if (tid == 63) acc += end_t[tags[(long)(S_LEN - 1) * B_SZ + b]];
    #pragma unroll
    for (int off = 32; off; off >>= 1) acc += __shfl_down(acc, off, 64);
    if (tid == 0) num[b] = acc;
}

// ---------------------------------------------------------------------------
// K6: CRF forward DP + final reduce. 1 wave/block, 3 batches/wave (lanes
//     (bl,j), 57 active). texp[i]=exp(trans[i][j]) in VGPRs. Double-buffered
//     score rows -> ONE barrier per step; per-lane local exps; max tree.
// ---------------------------------------------------------------------------
__global__ __launch_bounds__(64)
void k6_crf(const float* __restrict__ em, const float* __restrict__ trans,
            const float* __restrict__ start_t, const float* __restrict__ end_t,
            const float* __restrict__ num, float* __restrict__ out) {
    __shared__ float sbuf[2][3][20];        // rows 80B -> f4-aligned
    const int tid = threadIdx.x;
    const int bl  = tid / T_SZ;             // 0..2 for tid<57
    const int j   = tid - bl * T_SZ;
    const int b   = blockIdx.x * 3 + bl;
    const bool act = (tid < 57) && (b < B_SZ);

    float texp[T_SZ];
    float score = 0.f, em_cur = 0.f;
    if (act) {
        #pragma unroll
        for (int i = 0; i < T_SZ; ++i) texp[i] = __expf(trans[i * T_SZ + j]);
        score  = start_t[j] + em[(long)b * T_SZ + j];            // s=0
        em_cur = em[((long)1 * B_SZ + b) * T_SZ + j];            // prefetch s=1
    }

    int buf = 0;
    for (int s = 1; s < S_LEN; ++s) {
        float em_nxt = 0.f;
        if (act) {
            int sn = (s + 1 < S_LEN) ? (s + 1) : s;
            em_nxt = em[((long)sn * B_SZ + b) * T_SZ + j];       // prefetch
            sbuf[buf][bl][j] = score;
        }
        __syncthreads();
        if (act) {
            float4 v0 = *(const float4*)&sbuf[buf][bl][0];
            float4 v1 = *(const float4*)&sbuf[buf][bl][4];
            float4 v2 = *(const float4*)&sbuf[buf][bl][8];
            float4 v3 = *(const float4*)&sbuf[buf][bl][12];
            float4 v4 = *(const float4*)&sbuf[buf][bl][16];      // .w unused
            float sc[T_SZ] = {v0.x,v0.y,v0.z,v0.w, v1.x,v1.y,v1.z,v1.w,
                              v2.x,v2.y,v2.z,v2.w, v3.x,v3.y,v3.z,v3.w,
                              v4.x,v4.y,v4.z};
            float m = sc[0];
            #pragma unroll
            for (int i = 0; i < 9; ++i) m = fmaxf(fmaxf(m, sc[2*i+1]), sc[2*i+2]);
            float sum = 0.f;
            #pragma unroll
            for (int i = 0; i < T_SZ; ++i) sum = fmaf(__expf(sc[i] - m), texp[i], sum);
            score = m + __logf(sum) + em_cur;
        }
        em_cur = em_nxt;
        buf ^= 1;
    }

    if (act) sbuf[0][bl][j] = score + end_t[j];
    __syncthreads();
    if (act && j == 0) {
        float m = -1e30f;
        #pragma unroll
        for (int i = 0; i < T_SZ; ++i) m = fmaxf(m, sbuf[0][bl][i]);
        float sum = 0.f;
        #pragma unroll
        for (int i = 0; i < T_SZ; ++i) sum += __expf(sbuf[0][bl][i] - m);
        atomicAdd(out, num[b] - (m + __logf(sum)));
    }
}

// ---------------------------------------------------------------------------
extern "C" void kernel_launch(void* const* d_in, const int* in_sizes, int n_in,
                              void* d_out, int out_size, void* d_ws, size_t ws_size,
                              hipStream_t stream) {
    const float* x       = (const float*)d_in[0];
    const int*   tags    = (const int*)  d_in[1];
    const float* w_ih_f  = (const float*)d_in[2];
    const float* w_hh_f  = (const float*)d_in[3];
    const float* b_ih_f  = (const float*)d_in[4];
    const float* b_hh_f  = (const float*)d_in[5];
    const float* w_ih_b  = (const float*)d_in[6];
    const float* w_hh_b  = (const float*)d_in[7];
    const float* b_ih_b  = (const float*)d_in[8];
    const float* b_hh_b  = (const float*)d_in[9];
    const float* W_tag   = (const float*)d_in[10];
    const float* b_tag   = (const float*)d_in[11];
    const float* start_t = (const float*)d_in[12];
    const float* end_t   = (const float*)d_in[13];
    const float* trans   = (const float*)d_in[14];

    float* ws = (float*)d_ws;
    float* xf   = ws;                        // 13,107,200 fl (becomes hf in-place)
    float* xb   = xf + 13107200;             // 13,107,200 fl (becomes hb in-place)
    float* em   = xb + 13107200;             //  2,490,368 fl
    float* num  = em + 2490368;              //        256 fl
    float* wpad = num + 256;                 //     46,400 fl   (~115 MB total)

    k0_packw <<<200, 256, 0, stream>>>(w_ih_f, w_ih_b, wpad);
    k1_inproj<<<2048, 256, 0, stream>>>(x, wpad, b_ih_f, b_ih_b, xf, xb);
    k2_rnn   <<<512, 128, 0, stream>>>(w_hh_f, b_hh_f, w_hh_b, b_hh_b, xf, xb);
    k4_emis  <<<2048, 256, 0, stream>>>(xf, xb, W_tag, b_tag, em);
    k5_numer <<<256, 64, 0, stream>>>(tags, em, trans, start_t, end_t, num);
    hipMemsetAsync(d_out, 0, sizeof(float), stream);
    k6_crf   <<<86, 64, 0, stream>>>(em, trans, start_t, end_t, num, (float*)d_out);
}